// Round 3
// baseline (4983.004 us; speedup 1.0000x reference)
//
#include <hip/hip_runtime.h>
#include <hip/hip_bf16.h>
#include <math.h>

typedef __hip_bfloat16 bf16;
__device__ __forceinline__ float b2f(bf16 v){ return __bfloat162float(v); }
__device__ __forceinline__ bf16  f2b(float v){ return __float2bfloat16(v); }
__device__ __forceinline__ float LD(const bf16* p, size_t i){ return b2f(p[i]); }
__device__ __forceinline__ float LD(const float* p, size_t i){ return p[i]; }

#define BL 2048

// per-lane-row dot of N elements against an LDS vector (broadcast reads)
template<int N, typename T>
__device__ __forceinline__ float dotrow(const T* __restrict__ rowp, const float* __restrict__ xv) {
    float acc = 0.f;
    if constexpr (sizeof(T) == 2) {
        const uint4* r4 = reinterpret_cast<const uint4*>(rowp);
        #pragma unroll 4
        for (int u = 0; u < N / 8; u++) {
            union { uint4 q; bf16 h[8]; } c; c.q = r4[u];
            #pragma unroll
            for (int i = 0; i < 8; i++) acc += xv[u * 8 + i] * b2f(c.h[i]);
        }
    } else {
        const float4* r4 = reinterpret_cast<const float4*>(rowp);
        #pragma unroll 8
        for (int u = 0; u < N / 4; u++) {
            float4 p = r4[u];
            acc += xv[u * 4 + 0] * p.x + xv[u * 4 + 1] * p.y
                 + xv[u * 4 + 2] * p.z + xv[u * 4 + 3] * p.w;
        }
    }
    return acc;
}

// ---------- dtype sniff: rot rows are orthonormal (QR) ----------
__global__ void k_sniff(const void* rot, int* flag) {
    if (threadIdx.x == 0 && blockIdx.x == 0) {
        const bf16*  pb = (const bf16*)rot;
        const float* pf = (const float*)rot;
        float eb = 0.f, ef = 0.f;
        for (int r = 0; r < 8; r++) {
            float sb = 0.f, sf = 0.f;
            for (int c = 0; c < 3; c++) {
                float vb = b2f(pb[r * 9 + c]);
                float vf = pf[r * 9 + c];
                sb += vb * vb; sf += vf * vf;
            }
            eb += fabsf(sb - 1.f); ef += fabsf(sf - 1.f);
        }
        int okb = (eb < 0.5f) ? 1 : 0;
        int okf = (ef < 0.5f) ? 1 : 0;
        flag[0] = (okf && !okb) ? 0 : 1;
    }
}

// ---------- generic per-layer transpose: out[l][c][r] = in[l][r][c], same dtype ----------
__global__ void k_tr(const void* in, void* out, int R, int C, const int* __restrict__ flag) {
    int total = 6 * R * C;
    for (int idx = blockIdx.x * 256 + threadIdx.x; idx < total; idx += gridDim.x * 256) {
        int l = idx / (R * C); int rem = idx - l * (R * C);
        int r = rem / C, c = rem - r * C;
        size_t oidx = (size_t)l * R * C + (size_t)c * R + r;
        if (*flag) ((bf16*)out)[oidx]  = ((const bf16*)in)[idx];
        else       ((float*)out)[oidx] = ((const float*)in)[idx];
    }
}

// ---------- init ----------
__global__ void k_init(const void* rf, float* __restrict__ x, const int* __restrict__ flag) {
    int i = blockIdx.x * 256 + threadIdx.x;
    if (*flag) x[i] = b2f(((const bf16*)rf)[i]);
    else       x[i] = ((const float*)rf)[i];
}

// ---------- projections + frame transform ----------
// Weights are pre-transposed: W*T[l][col][128]. k/kp written transposed AND
// 4-col packed per batch: k4[b][col/4][j(256)][4] for uint2 logits loads.
template<typename T>
__device__ void proj_body(int row, int tid, int l, float* sm,
    const float* __restrict__ x,
    const T* WqT, const T* WkT, const T* WvT,
    const T* WqpT, const T* WkpT, const T* WvpT,
    const T* rot, const T* pos,
    bf16* q, bf16* k, bf16* v, bf16* qpg, bf16* kpg, bf16* vpg)
{
    float* xr = sm;           // 128
    float* ob = sm + 128;     // 2016
    float* Rm = sm + 2144;    // 9
    float* tv = sm + 2153;    // 3

    if (tid < 128)          xr[tid]       = x[(size_t)row * 128 + tid];
    else if (tid < 137)     Rm[tid - 128] = LD(rot, (size_t)row * 9 + (tid - 128));
    else if (tid < 140)     tv[tid - 137] = LD(pos, (size_t)row * 3 + (tid - 137));
    __syncthreads();

    for (int c = tid; c < 2016; c += 256) {
        const T* rowp;
        if (c < 1152) { int seg = c / 384; int col = c - seg * 384;
                        const T* W = (seg == 0) ? WqT : (seg == 1 ? WkT : WvT);
                        rowp = W + (size_t)l * 49152 + (size_t)col * 128; }
        else          { int seg = (c - 1152) / 288; int col = (c - 1152) - seg * 288;
                        const T* W = (seg == 0) ? WqpT : (seg == 1 ? WkpT : WvpT);
                        rowp = W + (size_t)l * 36864 + (size_t)col * 128; }
        ob[c] = dotrow<128>(rowp, xr);
    }
    __syncthreads();

    const int bb = row >> 8, ii = row & 255;

    for (int i2 = tid; i2 < 1152; i2 += 256) {
        bf16 val = f2b(ob[i2]);
        if (i2 < 384)      q[(size_t)row * 384 + i2] = val;
        else if (i2 < 768) {
            int col = i2 - 384;   // packed transposed
            k[(size_t)bb * 98304 + (size_t)(col >> 2) * 1024 + ii * 4 + (col & 3)] = val;
        }
        else               v[(size_t)row * 384 + (i2 - 768)] = val;
    }
    for (int pt = tid; pt < 288; pt += 256) {
        int ty = pt / 96; int ip = pt - ty * 96; int base = 1152 + ty * 288 + ip * 3;
        float p0 = ob[base], p1 = ob[base + 1], p2 = ob[base + 2];
        float g0 = Rm[0] * p0 + Rm[1] * p1 + Rm[2] * p2 + tv[0];
        float g1 = Rm[3] * p0 + Rm[4] * p1 + Rm[5] * p2 + tv[1];
        float g2 = Rm[6] * p0 + Rm[7] * p1 + Rm[8] * p2 + tv[2];
        float gg[3] = {g0, g1, g2};
        if (ty == 0) {
            qpg[(size_t)row * 288 + ip * 3 + 0] = f2b(g0);
            qpg[(size_t)row * 288 + ip * 3 + 1] = f2b(g1);
            qpg[(size_t)row * 288 + ip * 3 + 2] = f2b(g2);
        } else if (ty == 1) {  // packed transposed
            #pragma unroll
            for (int cc = 0; cc < 3; cc++) {
                int col = ip * 3 + cc;
                kpg[(size_t)bb * 73728 + (size_t)(col >> 2) * 1024 + ii * 4 + (col & 3)] = f2b(gg[cc]);
            }
        } else {
            vpg[(size_t)row * 288 + ip * 3 + 0] = f2b(g0);
            vpg[(size_t)row * 288 + ip * 3 + 1] = f2b(g1);
            vpg[(size_t)row * 288 + ip * 3 + 2] = f2b(g2);
        }
    }
}

__global__ __launch_bounds__(256) void k_proj(
    const float* __restrict__ x,
    const void* WqT, const void* WkT, const void* WvT,
    const void* WqpT, const void* WkpT, const void* WvpT,
    const void* rot, const void* pos,
    bf16* q, bf16* k, bf16* v, bf16* qpg, bf16* kpg, bf16* vpg,
    const int* __restrict__ flag, int l)
{
    extern __shared__ float smp[];
    int row = blockIdx.x, tid = threadIdx.x;
    if (*flag) proj_body<bf16>(row, tid, l, smp, x,
        (const bf16*)WqT, (const bf16*)WkT, (const bf16*)WvT,
        (const bf16*)WqpT, (const bf16*)WkpT, (const bf16*)WvpT,
        (const bf16*)rot, (const bf16*)pos, q, k, v, qpg, kpg, vpg);
    else proj_body<float>(row, tid, l, smp, x,
        (const float*)WqT, (const float*)WkT, (const float*)WvT,
        (const float*)WqpT, (const float*)WkpT, (const float*)WvpT,
        (const float*)rot, (const float*)pos, q, k, v, qpg, kpg, vpg);
}

// ---------- fused attention + Wo + LN1 + MLP + LN2 ----------
template<typename T>
__device__ void attn_body(int row, int tid, int l, char* smc,
    const bf16* q, const bf16* k, const bf16* v,
    const bf16* qpg, const bf16* kpg, const bf16* vpg,
    const T* z, const T* Wpb, const T* coef, const T* rot, const T* pos,
    float* __restrict__ x,
    const T* WoT, const T* bo, const T* g1, const T* b1ln,
    const T* w1T, const T* bb1, const T* w2T, const T* bb2,
    const T* w3T, const T* bb3, const T* g2, const T* b2ln)
{
    const size_t oWpb = (size_t)l * 768, oCo = (size_t)l * 12;
    const size_t oB = (size_t)l * 128;

    float* fsm = (float*)smc;
    float* al   = fsm;                            // 12 x 257 = 3084 (padded stride)
    float* fr   = fsm + 3084;                     // 1824
    float* qi   = fsm + 4908;                     // 384
    float* qpi  = fsm + 5292;                     // 288
    float* wpb  = fsm + 5580;                     // 768
    float* chv  = fsm + 6348;                     // 12
    float* Rm   = fsm + 6360;                     // 9
    float* tv   = fsm + 6369;                     // 3
    float (*red)[8] = (float(*)[8])(fsm + 6372);  // 96
    float* red2 = fsm + 6468;                     // 4
    // total 6472 floats = 25888 B

    int b = row >> 8;

    for (int c2 = tid; c2 < 384; c2 += 256) qi[c2]  = b2f(q[(size_t)row * 384 + c2]);
    for (int c2 = tid; c2 < 288; c2 += 256) qpi[c2] = b2f(qpg[(size_t)row * 288 + c2]);
    for (int c2 = tid; c2 < 768; c2 += 256) wpb[c2] = LD(Wpb, oWpb + c2);
    if (tid < 12) { float cc = LD(coef, oCo + tid); chv[tid] = -log1pf(expf(cc)) * (1.f / 12.f); }
    else if (tid >= 16 && tid < 25) Rm[tid - 16] = LD(rot, (size_t)row * 9 + (tid - 16));
    else if (tid >= 25 && tid < 28) tv[tid - 25] = LD(pos, (size_t)row * 3 + (tid - 25));
    __syncthreads();

    const int j = tid;
    float lg[12];
    #pragma unroll
    for (int h = 0; h < 12; h++) lg[h] = 0.f;

    // logits_pair: lane j consumes z[row][j][0..63] via vector loads
    if constexpr (sizeof(T) == 2) {
        const uint4* zr4 = reinterpret_cast<const uint4*>(z + (size_t)row * 16384 + (size_t)j * 64);
        #pragma unroll
        for (int u = 0; u < 8; u++) {
            union { uint4 q4; bf16 h8[8]; } c; c.q4 = zr4[u];
            #pragma unroll
            for (int dd = 0; dd < 8; dd++) {
                float zv = b2f(c.h8[dd]);
                const int d = u * 8 + dd;
                #pragma unroll
                for (int h = 0; h < 12; h++) lg[h] += zv * wpb[d * 12 + h];
            }
        }
    } else {
        const float4* zr4 = reinterpret_cast<const float4*>(z + (size_t)row * 16384 + (size_t)j * 64);
        #pragma unroll
        for (int u = 0; u < 16; u++) {
            float4 pk = zr4[u];
            float zz[4] = {pk.x, pk.y, pk.z, pk.w};
            #pragma unroll
            for (int dd = 0; dd < 4; dd++) {
                float zv = zz[dd];
                const int d = u * 4 + dd;
                #pragma unroll
                for (int h = 0; h < 12; h++) lg[h] += zv * wpb[d * 12 + h];
            }
        }
    }

    // packed transposed K / KP: uint2 (4 bf16 cols) per load, lane-coalesced
    const bf16* k4  = k   + (size_t)b * 98304;
    const bf16* kp4 = kpg + (size_t)b * 73728;
    #pragma unroll 2
    for (int h = 0; h < 12; h++) {
        float nd = 0.f;
        #pragma unroll
        for (int d4 = 0; d4 < 8; d4++) {
            union { uint2 q2; bf16 h4[4]; } c;
            c.q2 = *reinterpret_cast<const uint2*>(k4 + (size_t)(h * 8 + d4) * 1024 + j * 4);
            #pragma unroll
            for (int i = 0; i < 4; i++) nd += qi[h * 32 + d4 * 4 + i] * b2f(c.h4[i]);
        }
        float qk = 0.f, kp2h = 0.f, qp2h = 0.f;
        #pragma unroll
        for (int m4 = 0; m4 < 6; m4++) {
            union { uint2 q2; bf16 h4[4]; } c;
            c.q2 = *reinterpret_cast<const uint2*>(kp4 + (size_t)(h * 6 + m4) * 1024 + j * 4);
            #pragma unroll
            for (int i = 0; i < 4; i++) {
                float qv = qpi[h * 24 + m4 * 4 + i], kv = b2f(c.h4[i]);
                qk += qv * kv; kp2h += kv * kv; qp2h += qv * qv;
            }
        }
        float sp = chv[h] * (qp2h + kp2h - 2.f * qk);
        lg[h] = (lg[h] + nd * 0.17677669529663687f + sp) * 0.5773502691896258f;
    }

    int w = tid >> 6;
    #pragma unroll
    for (int h = 0; h < 12; h++) {
        float vv = lg[h];
        for (int off = 32; off; off >>= 1) vv = fmaxf(vv, __shfl_xor(vv, off, 64));
        if ((tid & 63) == 0) red[h][w] = vv;
    }
    __syncthreads();
    float mh[12];
    #pragma unroll
    for (int h = 0; h < 12; h++)
        mh[h] = fmaxf(fmaxf(red[h][0], red[h][1]), fmaxf(red[h][2], red[h][3]));
    #pragma unroll
    for (int h = 0; h < 12; h++) {
        float e = expf(lg[h] - mh[h]); lg[h] = e;
        float ss = e;
        for (int off = 32; off; off >>= 1) ss += __shfl_xor(ss, off, 64);
        if ((tid & 63) == 0) red[h][4 + w] = ss;
    }
    __syncthreads();
    #pragma unroll
    for (int h = 0; h < 12; h++) {
        float S = red[h][4] + red[h][5] + red[h][6] + red[h][7];
        al[h * 257 + j] = lg[h] / S;
    }
    __syncthreads();

    // aggregation: thread g produces 8 consecutive outputs, uint4 loads per jj
    {
        int g = tid;
        if (g < 180) {
            int h, dst_kind, dsto = 0, d0 = 0;
            const bf16* srcb = nullptr; int stride = 0;
            if (g < 48)       { h = g >> 2; dsto = g * 8;
                                srcb = v + (size_t)b * 98304 + dsto; stride = 384; dst_kind = 0; }
            else if (g < 144) { int gg = g - 48; h = gg >> 3; d0 = (gg & 7) * 8; dst_kind = 1; }
            else              { int gg = g - 144; h = gg / 3; dsto = gg * 8;
                                srcb = vpg + (size_t)b * 73728 + dsto; stride = 288; dst_kind = 2; }

            float acc[8];
            #pragma unroll
            for (int i = 0; i < 8; i++) acc[i] = 0.f;
            const float* alh = al + h * 257;

            if (dst_kind != 1) {
                for (int jj = 0; jj < 256; jj++) {
                    float a = alh[jj];
                    union { uint4 q4; bf16 h8[8]; } c;
                    c.q4 = *reinterpret_cast<const uint4*>(srcb + (size_t)jj * stride);
                    #pragma unroll
                    for (int i = 0; i < 8; i++) acc[i] += a * b2f(c.h8[i]);
                }
            } else {
                if constexpr (sizeof(T) == 2) {
                    const bf16* zr = (const bf16*)z + (size_t)row * 16384 + d0;
                    for (int jj = 0; jj < 256; jj++) {
                        float a = alh[jj];
                        union { uint4 q4; bf16 h8[8]; } c;
                        c.q4 = *reinterpret_cast<const uint4*>(zr + (size_t)jj * 64);
                        #pragma unroll
                        for (int i = 0; i < 8; i++) acc[i] += a * b2f(c.h8[i]);
                    }
                } else {
                    const float* zr = (const float*)z + (size_t)row * 16384 + d0;
                    for (int jj = 0; jj < 256; jj++) {
                        float a = alh[jj];
                        float4 p0 = *reinterpret_cast<const float4*>(zr + (size_t)jj * 64);
                        float4 p1 = *reinterpret_cast<const float4*>(zr + (size_t)jj * 64 + 4);
                        acc[0] += a * p0.x; acc[1] += a * p0.y; acc[2] += a * p0.z; acc[3] += a * p0.w;
                        acc[4] += a * p1.x; acc[5] += a * p1.y; acc[6] += a * p1.z; acc[7] += a * p1.w;
                    }
                }
            }
            if (dst_kind == 0) {
                #pragma unroll
                for (int i = 0; i < 8; i++) fr[dsto + i] = acc[i];
            } else if (dst_kind == 1) {
                int o = h * 64 + d0;
                #pragma unroll
                for (int i = 0; i < 8; i++) fr[384 + o + i] = acc[i];
            } else {
                #pragma unroll
                for (int i = 0; i < 8; i++) qpi[dsto + i] = acc[i];
            }
        }
    }
    __syncthreads();

    if (tid < 96) {
        int t3 = tid * 3;
        float u0 = qpi[t3 + 0] - tv[0], u1 = qpi[t3 + 1] - tv[1], u2 = qpi[t3 + 2] - tv[2];
        float f0 = Rm[0] * u0 + Rm[3] * u1 + Rm[6] * u2;
        float f1 = Rm[1] * u0 + Rm[4] * u1 + Rm[7] * u2;
        float f2 = Rm[2] * u0 + Rm[5] * u1 + Rm[8] * u2;
        float fd = sqrtf(f0 * f0 + f1 * f1 + f2 * f2);
        float inv = 1.f / (fd + 1e-4f);
        fr[1152 + t3 + 0] = f0; fr[1152 + t3 + 1] = f1; fr[1152 + t3 + 2] = f2;
        fr[1440 + tid] = fd;
        fr[1536 + t3 + 0] = f0 * inv; fr[1536 + t3 + 1] = f1 * inv; fr[1536 + t3 + 2] = f2 * inv;
    }
    __syncthreads();

    float* pacc = fsm;        // reuses dead al region
    float* shx  = fsm + 256;
    int col = tid & 127, half = tid >> 7;

    // Wo: pre-transposed, per-lane row, vectorized
    const T* worow = WoT + (size_t)l * 233472 + (size_t)col * 1824 + (size_t)half * 912;
    pacc[tid] = dotrow<912>(worow, fr + half * 912);
    __syncthreads();

    auto bsum = [&](float vv) -> float {
        for (int off = 32; off; off >>= 1) vv += __shfl_xor(vv, off, 64);
        if ((tid & 63) == 0) red2[tid >> 6] = vv;
        __syncthreads();
        float s = red2[0] + red2[1] + red2[2] + red2[3];
        __syncthreads();
        return s;
    };

    float val = x[(size_t)row * 128 + col] + LD(bo, oB + col) + pacc[col] + pacc[128 + col];

    float mean = bsum(val) * (1.f / 256.f);
    float dv = val - mean;
    float var = bsum(dv * dv) * (1.f / 256.f);
    float xl = dv * rsqrtf(var + 1e-5f) * LD(g1, oB + col) + LD(b1ln, oB + col);
    shx[col] = xl;
    __syncthreads();

    const size_t oM = (size_t)l * 16384;
    float a1 = LD(bb1, oB + col) + dotrow<128>(w1T + oM + (size_t)col * 128, shx);
    a1 = fmaxf(a1, 0.f);
    __syncthreads();
    shx[col] = a1;
    __syncthreads();

    float a2 = LD(bb2, oB + col) + dotrow<128>(w2T + oM + (size_t)col * 128, shx);
    a2 = fmaxf(a2, 0.f);
    __syncthreads();
    shx[col] = a2;
    __syncthreads();

    float a3 = LD(bb3, oB + col) + dotrow<128>(w3T + oM + (size_t)col * 128, shx);
    float val2 = xl + a3;

    float mean2 = bsum(val2) * (1.f / 256.f);
    float dv2 = val2 - mean2;
    float var2 = bsum(dv2 * dv2) * (1.f / 256.f);
    if (tid < 128)
        x[(size_t)row * 128 + col] = dv2 * rsqrtf(var2 + 1e-5f) * LD(g2, oB + col) + LD(b2ln, oB + col);
}

__global__ __launch_bounds__(256, 6) void k_attn_post(
    const bf16* q, const bf16* k, const bf16* v,
    const bf16* qpg, const bf16* kpg, const bf16* vpg,
    const void* z, const void* Wpb, const void* coef, const void* rot, const void* pos,
    float* x,
    const void* WoT, const void* bo, const void* g1, const void* b1ln,
    const void* w1T, const void* bb1, const void* w2T, const void* bb2,
    const void* w3T, const void* bb3, const void* g2, const void* b2ln,
    const int* __restrict__ flag, int l)
{
    extern __shared__ char smc[];
    int row = blockIdx.x, tid = threadIdx.x;
    if (*flag) attn_body<bf16>(row, tid, l, smc, q, k, v, qpg, kpg, vpg,
        (const bf16*)z, (const bf16*)Wpb, (const bf16*)coef, (const bf16*)rot, (const bf16*)pos, x,
        (const bf16*)WoT, (const bf16*)bo, (const bf16*)g1, (const bf16*)b1ln,
        (const bf16*)w1T, (const bf16*)bb1, (const bf16*)w2T, (const bf16*)bb2,
        (const bf16*)w3T, (const bf16*)bb3, (const bf16*)g2, (const bf16*)b2ln);
    else attn_body<float>(row, tid, l, smc, q, k, v, qpg, kpg, vpg,
        (const float*)z, (const float*)Wpb, (const float*)coef, (const float*)rot, (const float*)pos, x,
        (const float*)WoT, (const float*)bo, (const float*)g1, (const float*)b1ln,
        (const float*)w1T, (const float*)bb1, (const float*)w2T, (const float*)bb2,
        (const float*)w3T, (const float*)bb3, (const float*)g2, (const float*)b2ln);
}

// ---------- regression head ----------
__global__ void k_final(const float* __restrict__ x, const void* Wreg, const void* breg,
                        void* out, const int* __restrict__ flag)
{
    int idx = blockIdx.x * 256 + threadIdx.x;
    int isBF = *flag;
    int b = idx >> 7, r = (idx >> 2) & 31, c = idx & 3;
    const float* xr = x + ((size_t)(b * 256 + 224 + r)) * 128;
    if (isBF) {
        const bf16* W = (const bf16*)Wreg;
        float acc = b2f(((const bf16*)breg)[c]);
        for (int kk = 0; kk < 128; kk++) acc += xr[kk] * b2f(W[kk * 4 + c]);
        ((bf16*)out)[idx] = f2b(acc);
    } else {
        const float* W = (const float*)Wreg;
        float acc = ((const float*)breg)[c];
        for (int kk = 0; kk < 128; kk++) acc += xr[kk] * W[kk * 4 + c];
        ((float*)out)[idx] = acc;
    }
}

extern "C" void kernel_launch(void* const* d_in, const int* in_sizes, int n_in,
                              void* d_out, int out_size, void* d_ws, size_t ws_size,
                              hipStream_t stream)
{
    const void* rot  = d_in[0];
    const void* pos  = d_in[1];
    const void* resf = d_in[2];
    const void* pair = d_in[3];
    const void* Wq   = d_in[5];
    const void* Wk   = d_in[6];
    const void* Wv   = d_in[7];
    const void* Wpb  = d_in[8];
    const void* coef = d_in[9];
    const void* Wqp  = d_in[10];
    const void* Wkp  = d_in[11];
    const void* Wvp  = d_in[12];
    const void* Wo   = d_in[13];
    const void* bo   = d_in[14];
    const void* ln1g = d_in[15];
    const void* ln1b = d_in[16];
    const void* w1   = d_in[17];
    const void* b1   = d_in[18];
    const void* w2   = d_in[19];
    const void* b2   = d_in[20];
    const void* w3   = d_in[21];
    const void* b3   = d_in[22];
    const void* ln2g = d_in[23];
    const void* ln2b = d_in[24];
    const void* Wreg = d_in[25];
    const void* breg = d_in[26];

    char* base = (char*)d_ws;
    int*   flag = (int*)base;
    float* X    = (float*)(base + 64);
    size_t off  = 64 + (size_t)BL * 128 * 4;
    bf16* Qb   = (bf16*)(base + off); off += (size_t)BL * 384 * 2;
    bf16* Kb   = (bf16*)(base + off); off += (size_t)BL * 384 * 2;
    bf16* Vb   = (bf16*)(base + off); off += (size_t)BL * 384 * 2;
    bf16* QPGb = (bf16*)(base + off); off += (size_t)BL * 288 * 2;
    bf16* KPGb = (bf16*)(base + off); off += (size_t)BL * 288 * 2;
    bf16* VPGb = (bf16*)(base + off); off += (size_t)BL * 288 * 2;
    // transposed weights (sized for f32 worst case; bf16 mode uses half)
    void* WqT  = base + off; off += (size_t)6 * 384 * 128 * 4;
    void* WkT  = base + off; off += (size_t)6 * 384 * 128 * 4;
    void* WvT  = base + off; off += (size_t)6 * 384 * 128 * 4;
    void* WqpT = base + off; off += (size_t)6 * 288 * 128 * 4;
    void* WkpT = base + off; off += (size_t)6 * 288 * 128 * 4;
    void* WvpT = base + off; off += (size_t)6 * 288 * 128 * 4;
    void* WoT  = base + off; off += (size_t)6 * 1824 * 128 * 4;
    void* w1T  = base + off; off += (size_t)6 * 128 * 128 * 4;
    void* w2T  = base + off; off += (size_t)6 * 128 * 128 * 4;
    void* w3T  = base + off; off += (size_t)6 * 128 * 128 * 4;

    const size_t SM_PROJ = 2156 * sizeof(float);
    const size_t SM_ATTN = 6472 * sizeof(float);   // 25888 B

    k_sniff<<<1, 64, 0, stream>>>(rot, flag);

    auto TR = [&](const void* in, void* out, int R, int C) {
        int blocks = (6 * R * C + 255) / 256;
        k_tr<<<blocks, 256, 0, stream>>>(in, out, R, C, flag);
    };
    TR(Wq,  WqT, 128, 384);
    TR(Wk,  WkT, 128, 384);
    TR(Wv,  WvT, 128, 384);
    TR(Wqp, WqpT, 128, 288);
    TR(Wkp, WkpT, 128, 288);
    TR(Wvp, WvpT, 128, 288);
    TR(Wo,  WoT, 1824, 128);
    TR(w1,  w1T, 128, 128);
    TR(w2,  w2T, 128, 128);
    TR(w3,  w3T, 128, 128);

    k_init<<<BL * 128 / 256, 256, 0, stream>>>(resf, X, flag);

    for (int l = 0; l < 6; l++) {
        k_proj<<<BL, 256, SM_PROJ, stream>>>(
            X, WqT, WkT, WvT, WqpT, WkpT, WvpT, rot, pos,
            Qb, Kb, Vb, QPGb, KPGb, VPGb, flag, l);
        k_attn_post<<<BL, 256, SM_ATTN, stream>>>(
            Qb, Kb, Vb, QPGb, KPGb, VPGb,
            pair, Wpb, coef, rot, pos, X,
            WoT, bo, ln1g, ln1b, w1T, b1, w2T, b2, w3T, b3, ln2g, ln2b, flag, l);
    }

    k_final<<<4, 256, 0, stream>>>(X, Wreg, breg, d_out, flag);
}

// Round 4
// 3320.255 us; speedup vs baseline: 1.5008x; 1.5008x over previous
//
#include <hip/hip_runtime.h>
#include <hip/hip_bf16.h>
#include <math.h>

typedef __hip_bfloat16 bf16;
__device__ __forceinline__ float b2f(bf16 v){ return __bfloat162float(v); }
__device__ __forceinline__ bf16  f2b(float v){ return __float2bfloat16(v); }
__device__ __forceinline__ float LD(const bf16* p, size_t i){ return b2f(p[i]); }
__device__ __forceinline__ float LD(const float* p, size_t i){ return p[i]; }

#define BL 2048

// ---------- dtype sniff: rot rows are orthonormal (QR) ----------
__global__ void k_sniff(const void* rot, int* flag) {
    if (threadIdx.x == 0 && blockIdx.x == 0) {
        const bf16*  pb = (const bf16*)rot;
        const float* pf = (const float*)rot;
        float eb = 0.f, ef = 0.f;
        for (int r = 0; r < 8; r++) {
            float sb = 0.f, sf = 0.f;
            for (int c = 0; c < 3; c++) {
                float vb = b2f(pb[r * 9 + c]);
                float vf = pf[r * 9 + c];
                sb += vb * vb; sf += vf * vf;
            }
            eb += fabsf(sb - 1.f); ef += fabsf(sf - 1.f);
        }
        int okb = (eb < 0.5f) ? 1 : 0;
        int okf = (ef < 0.5f) ? 1 : 0;
        flag[0] = (okf && !okb) ? 0 : 1;
    }
}

// ---------- init ----------
__global__ void k_init(const void* rf, float* __restrict__ x, const int* __restrict__ flag) {
    int i = blockIdx.x * 256 + threadIdx.x;
    if (*flag) x[i] = b2f(((const bf16*)rf)[i]);
    else       x[i] = ((const float*)rf)[i];
}

// ---------- projections + frame transform ----------
// Original weight layouts W[l][kk(128)][col]. Each thread computes 4 consecutive
// output cols via uint2/float4 loads of W[kk][c0..c0+3] -> coalesced across lanes.
// k/kp written transposed AND 4-col packed per batch: k4[b][col/4][j(256)][4].
template<typename T>
__device__ void proj_body(int row, int tid, int l, float* sm,
    const float* __restrict__ x,
    const T* Wq, const T* Wk, const T* Wv,
    const T* Wqp, const T* Wkp, const T* Wvp,
    const T* rot, const T* pos,
    bf16* q, bf16* k, bf16* v, bf16* qpg, bf16* kpg, bf16* vpg)
{
    float* xr = sm;           // 128
    float* ob = sm + 128;     // 2016
    float* Rm = sm + 2144;    // 9
    float* tv = sm + 2153;    // 3

    if (tid < 128)          xr[tid]       = x[(size_t)row * 128 + tid];
    else if (tid < 137)     Rm[tid - 128] = LD(rot, (size_t)row * 9 + (tid - 128));
    else if (tid < 140)     tv[tid - 137] = LD(pos, (size_t)row * 3 + (tid - 137));
    __syncthreads();

    for (int c4 = tid; c4 < 504; c4 += 256) {
        int c = c4 * 4;
        const T* W; int col, wc;
        if (c < 1152) { int seg = c / 384; col = c - seg * 384; wc = 384;
                        W = ((seg == 0) ? Wq : (seg == 1 ? Wk : Wv)) + (size_t)l * 49152; }
        else          { int c2 = c - 1152; int seg = c2 / 288; col = c2 - seg * 288; wc = 288;
                        W = ((seg == 0) ? Wqp : (seg == 1 ? Wkp : Wvp)) + (size_t)l * 36864; }
        float a0 = 0.f, a1 = 0.f, a2 = 0.f, a3 = 0.f;
        if constexpr (sizeof(T) == 2) {
            const bf16* wp = (const bf16*)W + col;
            #pragma unroll 8
            for (int kk = 0; kk < 128; kk++) {
                union { uint2 u; bf16 h[4]; } cv;
                cv.u = *reinterpret_cast<const uint2*>(wp + (size_t)kk * wc);
                float xv = xr[kk];
                a0 += xv * b2f(cv.h[0]); a1 += xv * b2f(cv.h[1]);
                a2 += xv * b2f(cv.h[2]); a3 += xv * b2f(cv.h[3]);
            }
        } else {
            const float* wp = (const float*)W + col;
            #pragma unroll 8
            for (int kk = 0; kk < 128; kk++) {
                float4 p = *reinterpret_cast<const float4*>(wp + (size_t)kk * wc);
                float xv = xr[kk];
                a0 += xv * p.x; a1 += xv * p.y; a2 += xv * p.z; a3 += xv * p.w;
            }
        }
        ob[c] = a0; ob[c + 1] = a1; ob[c + 2] = a2; ob[c + 3] = a3;
    }
    __syncthreads();

    const int bb = row >> 8, ii = row & 255;

    for (int i2 = tid; i2 < 1152; i2 += 256) {
        bf16 val = f2b(ob[i2]);
        if (i2 < 384)      q[(size_t)row * 384 + i2] = val;
        else if (i2 < 768) {
            int col = i2 - 384;   // packed transposed
            k[(size_t)bb * 98304 + (size_t)(col >> 2) * 1024 + ii * 4 + (col & 3)] = val;
        }
        else               v[(size_t)row * 384 + (i2 - 768)] = val;
    }
    for (int pt = tid; pt < 288; pt += 256) {
        int ty = pt / 96; int ip = pt - ty * 96; int base = 1152 + ty * 288 + ip * 3;
        float p0 = ob[base], p1 = ob[base + 1], p2 = ob[base + 2];
        float g0 = Rm[0] * p0 + Rm[1] * p1 + Rm[2] * p2 + tv[0];
        float g1 = Rm[3] * p0 + Rm[4] * p1 + Rm[5] * p2 + tv[1];
        float g2 = Rm[6] * p0 + Rm[7] * p1 + Rm[8] * p2 + tv[2];
        float gg[3] = {g0, g1, g2};
        if (ty == 0) {
            qpg[(size_t)row * 288 + ip * 3 + 0] = f2b(g0);
            qpg[(size_t)row * 288 + ip * 3 + 1] = f2b(g1);
            qpg[(size_t)row * 288 + ip * 3 + 2] = f2b(g2);
        } else if (ty == 1) {  // packed transposed
            #pragma unroll
            for (int cc = 0; cc < 3; cc++) {
                int col = ip * 3 + cc;
                kpg[(size_t)bb * 73728 + (size_t)(col >> 2) * 1024 + ii * 4 + (col & 3)] = f2b(gg[cc]);
            }
        } else {
            vpg[(size_t)row * 288 + ip * 3 + 0] = f2b(g0);
            vpg[(size_t)row * 288 + ip * 3 + 1] = f2b(g1);
            vpg[(size_t)row * 288 + ip * 3 + 2] = f2b(g2);
        }
    }
}

__global__ __launch_bounds__(256) void k_proj(
    const float* __restrict__ x,
    const void* Wq, const void* Wk, const void* Wv,
    const void* Wqp, const void* Wkp, const void* Wvp,
    const void* rot, const void* pos,
    bf16* q, bf16* k, bf16* v, bf16* qpg, bf16* kpg, bf16* vpg,
    const int* __restrict__ flag, int l)
{
    extern __shared__ float smp[];
    int row = blockIdx.x, tid = threadIdx.x;
    if (*flag) proj_body<bf16>(row, tid, l, smp, x,
        (const bf16*)Wq, (const bf16*)Wk, (const bf16*)Wv,
        (const bf16*)Wqp, (const bf16*)Wkp, (const bf16*)Wvp,
        (const bf16*)rot, (const bf16*)pos, q, k, v, qpg, kpg, vpg);
    else proj_body<float>(row, tid, l, smp, x,
        (const float*)Wq, (const float*)Wk, (const float*)Wv,
        (const float*)Wqp, (const float*)Wkp, (const float*)Wvp,
        (const float*)rot, (const float*)pos, q, k, v, qpg, kpg, vpg);
}

// ---------- fused attention + Wo + LN1 + MLP + LN2 ----------
template<typename T>
__device__ void attn_body(int row, int tid, int l, char* smc,
    const bf16* q, const bf16* k, const bf16* v,
    const bf16* qpg, const bf16* kpg, const bf16* vpg,
    const T* z, const T* Wpb, const T* coef, const T* rot, const T* pos,
    float* __restrict__ x,
    const T* Wo, const T* bo, const T* g1, const T* b1ln,
    const T* w1, const T* bb1, const T* w2, const T* bb2,
    const T* w3, const T* bb3, const T* g2, const T* b2ln)
{
    const size_t oWpb = (size_t)l * 768, oCo = (size_t)l * 12;
    const size_t oB = (size_t)l * 128;

    float* fsm = (float*)smc;
    float* al   = fsm;                            // 12 x 257 = 3084 (padded stride)
    float* fr   = fsm + 3084;                     // 1824
    float* qi   = fsm + 4908;                     // 384
    float* qpi  = fsm + 5292;                     // 288
    float* wpb  = fsm + 5580;                     // 768
    float* chv  = fsm + 6348;                     // 12
    float* Rm   = fsm + 6360;                     // 9
    float* tv   = fsm + 6369;                     // 3
    float (*red)[8] = (float(*)[8])(fsm + 6372);  // 96
    float* red2 = fsm + 6468;                     // 4
    // total 6472 floats = 25888 B

    int b = row >> 8;

    for (int c2 = tid; c2 < 384; c2 += 256) qi[c2]  = b2f(q[(size_t)row * 384 + c2]);
    for (int c2 = tid; c2 < 288; c2 += 256) qpi[c2] = b2f(qpg[(size_t)row * 288 + c2]);
    for (int c2 = tid; c2 < 768; c2 += 256) wpb[c2] = LD(Wpb, oWpb + c2);
    if (tid < 12) { float cc = LD(coef, oCo + tid); chv[tid] = -log1pf(expf(cc)) * (1.f / 12.f); }
    else if (tid >= 16 && tid < 25) Rm[tid - 16] = LD(rot, (size_t)row * 9 + (tid - 16));
    else if (tid >= 25 && tid < 28) tv[tid - 25] = LD(pos, (size_t)row * 3 + (tid - 25));
    __syncthreads();

    const int j = tid;
    float lg[12];
    #pragma unroll
    for (int h = 0; h < 12; h++) lg[h] = 0.f;

    // logits_pair: lane j consumes z[row][j][0..63] via vector loads
    if constexpr (sizeof(T) == 2) {
        const uint4* zr4 = reinterpret_cast<const uint4*>(z + (size_t)row * 16384 + (size_t)j * 64);
        #pragma unroll
        for (int u = 0; u < 8; u++) {
            union { uint4 q4; bf16 h8[8]; } c; c.q4 = zr4[u];
            #pragma unroll
            for (int dd = 0; dd < 8; dd++) {
                float zv = b2f(c.h8[dd]);
                const int d = u * 8 + dd;
                #pragma unroll
                for (int h = 0; h < 12; h++) lg[h] += zv * wpb[d * 12 + h];
            }
        }
    } else {
        const float4* zr4 = reinterpret_cast<const float4*>(z + (size_t)row * 16384 + (size_t)j * 64);
        #pragma unroll
        for (int u = 0; u < 16; u++) {
            float4 pk = zr4[u];
            float zz[4] = {pk.x, pk.y, pk.z, pk.w};
            #pragma unroll
            for (int dd = 0; dd < 4; dd++) {
                float zv = zz[dd];
                const int d = u * 4 + dd;
                #pragma unroll
                for (int h = 0; h < 12; h++) lg[h] += zv * wpb[d * 12 + h];
            }
        }
    }

    // packed transposed K / KP: uint2 (4 bf16 cols) per load, lane-coalesced
    const bf16* k4  = k   + (size_t)b * 98304;
    const bf16* kp4 = kpg + (size_t)b * 73728;
    #pragma unroll 2
    for (int h = 0; h < 12; h++) {
        float nd = 0.f;
        #pragma unroll
        for (int d4 = 0; d4 < 8; d4++) {
            union { uint2 q2; bf16 h4[4]; } c;
            c.q2 = *reinterpret_cast<const uint2*>(k4 + (size_t)(h * 8 + d4) * 1024 + j * 4);
            #pragma unroll
            for (int i = 0; i < 4; i++) nd += qi[h * 32 + d4 * 4 + i] * b2f(c.h4[i]);
        }
        float qk = 0.f, kp2h = 0.f, qp2h = 0.f;
        #pragma unroll
        for (int m4 = 0; m4 < 6; m4++) {
            union { uint2 q2; bf16 h4[4]; } c;
            c.q2 = *reinterpret_cast<const uint2*>(kp4 + (size_t)(h * 6 + m4) * 1024 + j * 4);
            #pragma unroll
            for (int i = 0; i < 4; i++) {
                float qv = qpi[h * 24 + m4 * 4 + i], kv = b2f(c.h4[i]);
                qk += qv * kv; kp2h += kv * kv; qp2h += qv * qv;
            }
        }
        float sp = chv[h] * (qp2h + kp2h - 2.f * qk);
        lg[h] = (lg[h] + nd * 0.17677669529663687f + sp) * 0.5773502691896258f;
    }

    int w = tid >> 6;
    #pragma unroll
    for (int h = 0; h < 12; h++) {
        float vv = lg[h];
        for (int off = 32; off; off >>= 1) vv = fmaxf(vv, __shfl_xor(vv, off, 64));
        if ((tid & 63) == 0) red[h][w] = vv;
    }
    __syncthreads();
    float mh[12];
    #pragma unroll
    for (int h = 0; h < 12; h++)
        mh[h] = fmaxf(fmaxf(red[h][0], red[h][1]), fmaxf(red[h][2], red[h][3]));
    #pragma unroll
    for (int h = 0; h < 12; h++) {
        float e = expf(lg[h] - mh[h]); lg[h] = e;
        float ss = e;
        for (int off = 32; off; off >>= 1) ss += __shfl_xor(ss, off, 64);
        if ((tid & 63) == 0) red[h][4 + w] = ss;
    }
    __syncthreads();
    #pragma unroll
    for (int h = 0; h < 12; h++) {
        float S = red[h][4] + red[h][5] + red[h][6] + red[h][7];
        al[h * 257 + j] = lg[h] / S;
    }
    __syncthreads();

    // aggregation: thread g produces 8 consecutive outputs, uint4 loads per jj
    {
        int g = tid;
        if (g < 180) {
            int h, dst_kind, dsto = 0, d0 = 0;
            const bf16* srcb = nullptr; int stride = 0;
            if (g < 48)       { h = g >> 2; dsto = g * 8;
                                srcb = v + (size_t)b * 98304 + dsto; stride = 384; dst_kind = 0; }
            else if (g < 144) { int gg = g - 48; h = gg >> 3; d0 = (gg & 7) * 8; dst_kind = 1; }
            else              { int gg = g - 144; h = gg / 3; dsto = gg * 8;
                                srcb = vpg + (size_t)b * 73728 + dsto; stride = 288; dst_kind = 2; }

            float acc[8];
            #pragma unroll
            for (int i = 0; i < 8; i++) acc[i] = 0.f;
            const float* alh = al + h * 257;

            if (dst_kind != 1) {
                for (int jj = 0; jj < 256; jj++) {
                    float a = alh[jj];
                    union { uint4 q4; bf16 h8[8]; } c;
                    c.q4 = *reinterpret_cast<const uint4*>(srcb + (size_t)jj * stride);
                    #pragma unroll
                    for (int i = 0; i < 8; i++) acc[i] += a * b2f(c.h8[i]);
                }
            } else {
                if constexpr (sizeof(T) == 2) {
                    const bf16* zr = (const bf16*)z + (size_t)row * 16384 + d0;
                    for (int jj = 0; jj < 256; jj++) {
                        float a = alh[jj];
                        union { uint4 q4; bf16 h8[8]; } c;
                        c.q4 = *reinterpret_cast<const uint4*>(zr + (size_t)jj * 64);
                        #pragma unroll
                        for (int i = 0; i < 8; i++) acc[i] += a * b2f(c.h8[i]);
                    }
                } else {
                    const float* zr = (const float*)z + (size_t)row * 16384 + d0;
                    for (int jj = 0; jj < 256; jj++) {
                        float a = alh[jj];
                        float4 p0 = *reinterpret_cast<const float4*>(zr + (size_t)jj * 64);
                        float4 p1 = *reinterpret_cast<const float4*>(zr + (size_t)jj * 64 + 4);
                        acc[0] += a * p0.x; acc[1] += a * p0.y; acc[2] += a * p0.z; acc[3] += a * p0.w;
                        acc[4] += a * p1.x; acc[5] += a * p1.y; acc[6] += a * p1.z; acc[7] += a * p1.w;
                    }
                }
            }
            if (dst_kind == 0) {
                #pragma unroll
                for (int i = 0; i < 8; i++) fr[dsto + i] = acc[i];
            } else if (dst_kind == 1) {
                int o = h * 64 + d0;
                #pragma unroll
                for (int i = 0; i < 8; i++) fr[384 + o + i] = acc[i];
            } else {
                #pragma unroll
                for (int i = 0; i < 8; i++) qpi[dsto + i] = acc[i];
            }
        }
    }
    __syncthreads();

    if (tid < 96) {
        int t3 = tid * 3;
        float u0 = qpi[t3 + 0] - tv[0], u1 = qpi[t3 + 1] - tv[1], u2 = qpi[t3 + 2] - tv[2];
        float f0 = Rm[0] * u0 + Rm[3] * u1 + Rm[6] * u2;
        float f1 = Rm[1] * u0 + Rm[4] * u1 + Rm[7] * u2;
        float f2 = Rm[2] * u0 + Rm[5] * u1 + Rm[8] * u2;
        float fd = sqrtf(f0 * f0 + f1 * f1 + f2 * f2);
        float inv = 1.f / (fd + 1e-4f);
        fr[1152 + t3 + 0] = f0; fr[1152 + t3 + 1] = f1; fr[1152 + t3 + 2] = f2;
        fr[1440 + tid] = fd;
        fr[1536 + t3 + 0] = f0 * inv; fr[1536 + t3 + 1] = f1 * inv; fr[1536 + t3 + 2] = f2 * inv;
    }
    __syncthreads();

    // ---- Wo: original layout Wo[l][kk(1824)][col(128)], 32 col-groups x 8 kk-splits ----
    float* pacc = fsm;          // [8][128] = 1024 floats (al region is dead)
    float* shx  = fsm + 1024;   // 128
    int col = tid & 127;
    {
        int gC = tid & 31, s = tid >> 5;
        int c0 = gC * 4, kk0 = s * 228;
        float a0 = 0.f, a1p = 0.f, a2p = 0.f, a3p = 0.f;
        if constexpr (sizeof(T) == 2) {
            const bf16* wp = (const bf16*)Wo + (size_t)l * 233472 + c0;
            #pragma unroll 4
            for (int kk = kk0; kk < kk0 + 228; kk++) {
                union { uint2 u; bf16 h[4]; } cv;
                cv.u = *reinterpret_cast<const uint2*>(wp + (size_t)kk * 128);
                float f = fr[kk];
                a0 += f * b2f(cv.h[0]); a1p += f * b2f(cv.h[1]);
                a2p += f * b2f(cv.h[2]); a3p += f * b2f(cv.h[3]);
            }
        } else {
            const float* wp = (const float*)Wo + (size_t)l * 233472 + c0;
            #pragma unroll 4
            for (int kk = kk0; kk < kk0 + 228; kk++) {
                float4 p = *reinterpret_cast<const float4*>(wp + (size_t)kk * 128);
                float f = fr[kk];
                a0 += f * p.x; a1p += f * p.y; a2p += f * p.z; a3p += f * p.w;
            }
        }
        pacc[s * 128 + c0 + 0] = a0;  pacc[s * 128 + c0 + 1] = a1p;
        pacc[s * 128 + c0 + 2] = a2p; pacc[s * 128 + c0 + 3] = a3p;
    }
    __syncthreads();

    auto bsum = [&](float vv) -> float {
        for (int off = 32; off; off >>= 1) vv += __shfl_xor(vv, off, 64);
        if ((tid & 63) == 0) red2[tid >> 6] = vv;
        __syncthreads();
        float s = red2[0] + red2[1] + red2[2] + red2[3];
        __syncthreads();
        return s;
    };

    float val = x[(size_t)row * 128 + col] + LD(bo, oB + col);
    #pragma unroll
    for (int s = 0; s < 8; s++) val += pacc[s * 128 + col];

    float mean = bsum(val) * (1.f / 256.f);
    float dv = val - mean;
    float var = bsum(dv * dv) * (1.f / 256.f);
    float xl = dv * rsqrtf(var + 1e-5f) * LD(g1, oB + col) + LD(b1ln, oB + col);
    shx[col] = xl;
    __syncthreads();

    // ---- MLP: original layout w[l][kk(128)][col(128)], 32 col-groups x 8 kk-splits ----
    const size_t oM = (size_t)l * 16384;
    int gC = tid & 31, s8 = tid >> 5;
    int c0 = gC * 4, kkm = s8 * 16;

    auto mlp_partial = [&](const T* W) {
        float a0 = 0.f, a1p = 0.f, a2p = 0.f, a3p = 0.f;
        if constexpr (sizeof(T) == 2) {
            const bf16* wp = (const bf16*)W + oM + c0;
            #pragma unroll
            for (int kk = kkm; kk < kkm + 16; kk++) {
                union { uint2 u; bf16 h[4]; } cv;
                cv.u = *reinterpret_cast<const uint2*>(wp + (size_t)kk * 128);
                float f = shx[kk];
                a0 += f * b2f(cv.h[0]); a1p += f * b2f(cv.h[1]);
                a2p += f * b2f(cv.h[2]); a3p += f * b2f(cv.h[3]);
            }
        } else {
            const float* wp = (const float*)W + oM + c0;
            #pragma unroll
            for (int kk = kkm; kk < kkm + 16; kk++) {
                float4 p = *reinterpret_cast<const float4*>(wp + (size_t)kk * 128);
                float f = shx[kk];
                a0 += f * p.x; a1p += f * p.y; a2p += f * p.z; a3p += f * p.w;
            }
        }
        pacc[s8 * 128 + c0 + 0] = a0;  pacc[s8 * 128 + c0 + 1] = a1p;
        pacc[s8 * 128 + c0 + 2] = a2p; pacc[s8 * 128 + c0 + 3] = a3p;
    };

    mlp_partial(w1);
    __syncthreads();
    float a1 = LD(bb1, oB + col);
    #pragma unroll
    for (int s = 0; s < 8; s++) a1 += pacc[s * 128 + col];
    a1 = fmaxf(a1, 0.f);
    __syncthreads();
    shx[col] = a1;
    __syncthreads();

    mlp_partial(w2);
    __syncthreads();
    float a2 = LD(bb2, oB + col);
    #pragma unroll
    for (int s = 0; s < 8; s++) a2 += pacc[s * 128 + col];
    a2 = fmaxf(a2, 0.f);
    __syncthreads();
    shx[col] = a2;
    __syncthreads();

    mlp_partial(w3);
    __syncthreads();
    float a3 = LD(bb3, oB + col);
    #pragma unroll
    for (int s = 0; s < 8; s++) a3 += pacc[s * 128 + col];
    float val2 = xl + a3;

    float mean2 = bsum(val2) * (1.f / 256.f);
    float dv2 = val2 - mean2;
    float var2 = bsum(dv2 * dv2) * (1.f / 256.f);
    if (tid < 128)
        x[(size_t)row * 128 + col] = dv2 * rsqrtf(var2 + 1e-5f) * LD(g2, oB + col) + LD(b2ln, oB + col);
}

__global__ __launch_bounds__(256, 6) void k_attn_post(
    const bf16* q, const bf16* k, const bf16* v,
    const bf16* qpg, const bf16* kpg, const bf16* vpg,
    const void* z, const void* Wpb, const void* coef, const void* rot, const void* pos,
    float* x,
    const void* Wo, const void* bo, const void* g1, const void* b1ln,
    const void* w1, const void* bb1, const void* w2, const void* bb2,
    const void* w3, const void* bb3, const void* g2, const void* b2ln,
    const int* __restrict__ flag, int l)
{
    extern __shared__ char smc[];
    int row = blockIdx.x, tid = threadIdx.x;
    if (*flag) attn_body<bf16>(row, tid, l, smc, q, k, v, qpg, kpg, vpg,
        (const bf16*)z, (const bf16*)Wpb, (const bf16*)coef, (const bf16*)rot, (const bf16*)pos, x,
        (const bf16*)Wo, (const bf16*)bo, (const bf16*)g1, (const bf16*)b1ln,
        (const bf16*)w1, (const bf16*)bb1, (const bf16*)w2, (const bf16*)bb2,
        (const bf16*)w3, (const bf16*)bb3, (const bf16*)g2, (const bf16*)b2ln);
    else attn_body<float>(row, tid, l, smc, q, k, v, qpg, kpg, vpg,
        (const float*)z, (const float*)Wpb, (const float*)coef, (const float*)rot, (const float*)pos, x,
        (const float*)Wo, (const float*)bo, (const float*)g1, (const float*)b1ln,
        (const float*)w1, (const float*)bb1, (const float*)w2, (const float*)bb2,
        (const float*)w3, (const float*)bb3, (const float*)g2, (const float*)b2ln);
}

// ---------- regression head ----------
__global__ void k_final(const float* __restrict__ x, const void* Wreg, const void* breg,
                        void* out, const int* __restrict__ flag)
{
    int idx = blockIdx.x * 256 + threadIdx.x;
    int isBF = *flag;
    int b = idx >> 7, r = (idx >> 2) & 31, c = idx & 3;
    const float* xr = x + ((size_t)(b * 256 + 224 + r)) * 128;
    if (isBF) {
        const bf16* W = (const bf16*)Wreg;
        float acc = b2f(((const bf16*)breg)[c]);
        for (int kk = 0; kk < 128; kk++) acc += xr[kk] * b2f(W[kk * 4 + c]);
        ((bf16*)out)[idx] = f2b(acc);
    } else {
        const float* W = (const float*)Wreg;
        float acc = ((const float*)breg)[c];
        for (int kk = 0; kk < 128; kk++) acc += xr[kk] * W[kk * 4 + c];
        ((float*)out)[idx] = acc;
    }
}

extern "C" void kernel_launch(void* const* d_in, const int* in_sizes, int n_in,
                              void* d_out, int out_size, void* d_ws, size_t ws_size,
                              hipStream_t stream)
{
    const void* rot  = d_in[0];
    const void* pos  = d_in[1];
    const void* resf = d_in[2];
    const void* pair = d_in[3];
    const void* Wq   = d_in[5];
    const void* Wk   = d_in[6];
    const void* Wv   = d_in[7];
    const void* Wpb  = d_in[8];
    const void* coef = d_in[9];
    const void* Wqp  = d_in[10];
    const void* Wkp  = d_in[11];
    const void* Wvp  = d_in[12];
    const void* Wo   = d_in[13];
    const void* bo   = d_in[14];
    const void* ln1g = d_in[15];
    const void* ln1b = d_in[16];
    const void* w1   = d_in[17];
    const void* b1   = d_in[18];
    const void* w2   = d_in[19];
    const void* b2   = d_in[20];
    const void* w3   = d_in[21];
    const void* b3   = d_in[22];
    const void* ln2g = d_in[23];
    const void* ln2b = d_in[24];
    const void* Wreg = d_in[25];
    const void* breg = d_in[26];

    char* base = (char*)d_ws;
    int*   flag = (int*)base;
    float* X    = (float*)(base + 64);
    size_t off  = 64 + (size_t)BL * 128 * 4;
    bf16* Qb   = (bf16*)(base + off); off += (size_t)BL * 384 * 2;
    bf16* Kb   = (bf16*)(base + off); off += (size_t)BL * 384 * 2;
    bf16* Vb   = (bf16*)(base + off); off += (size_t)BL * 384 * 2;
    bf16* QPGb = (bf16*)(base + off); off += (size_t)BL * 288 * 2;
    bf16* KPGb = (bf16*)(base + off); off += (size_t)BL * 288 * 2;
    bf16* VPGb = (bf16*)(base + off); off += (size_t)BL * 288 * 2;

    const size_t SM_PROJ = 2156 * sizeof(float);
    const size_t SM_ATTN = 6472 * sizeof(float);   // 25888 B

    k_sniff<<<1, 64, 0, stream>>>(rot, flag);
    k_init<<<BL * 128 / 256, 256, 0, stream>>>(resf, X, flag);

    for (int l = 0; l < 6; l++) {
        k_proj<<<BL, 256, SM_PROJ, stream>>>(
            X, Wq, Wk, Wv, Wqp, Wkp, Wvp, rot, pos,
            Qb, Kb, Vb, QPGb, KPGb, VPGb, flag, l);
        k_attn_post<<<BL, 256, SM_ATTN, stream>>>(
            Qb, Kb, Vb, QPGb, KPGb, VPGb,
            pair, Wpb, coef, rot, pos, X,
            Wo, bo, ln1g, ln1b, w1, b1, w2, b2, w3, b3, ln2g, ln2b, flag, l);
    }

    k_final<<<4, 256, 0, stream>>>(X, Wreg, breg, d_out, flag);
}

// Round 6
// 2422.280 us; speedup vs baseline: 2.0572x; 1.3707x over previous
//
#include <hip/hip_runtime.h>
#include <hip/hip_bf16.h>
#include <math.h>

typedef __hip_bfloat16 bf16;
__device__ __forceinline__ float b2f(bf16 v){ return __bfloat162float(v); }
__device__ __forceinline__ bf16  f2b(float v){ return __float2bfloat16(v); }
__device__ __forceinline__ float LD(const bf16* p, size_t i){ return b2f(p[i]); }
__device__ __forceinline__ float LD(const float* p, size_t i){ return p[i]; }

#define BL 2048
#define AST 260   // alpha LDS row stride (floats): multiple of 4 -> 16B-aligned float4 rows

// ---------- dtype sniff: rot rows are orthonormal (QR) ----------
__global__ void k_sniff(const void* rot, int* flag) {
    if (threadIdx.x == 0 && blockIdx.x == 0) {
        const bf16*  pb = (const bf16*)rot;
        const float* pf = (const float*)rot;
        float eb = 0.f, ef = 0.f;
        for (int r = 0; r < 8; r++) {
            float sb = 0.f, sf = 0.f;
            for (int c = 0; c < 3; c++) {
                float vb = b2f(pb[r * 9 + c]);
                float vf = pf[r * 9 + c];
                sb += vb * vb; sf += vf * vf;
            }
            eb += fabsf(sb - 1.f); ef += fabsf(sf - 1.f);
        }
        int okb = (eb < 0.5f) ? 1 : 0;
        int okf = (ef < 0.5f) ? 1 : 0;
        flag[0] = (okf && !okb) ? 0 : 1;
    }
}

// ---------- init ----------
__global__ void k_init(const void* rf, float* __restrict__ x, const int* __restrict__ flag) {
    int i = blockIdx.x * 256 + threadIdx.x;
    if (*flag) x[i] = b2f(((const bf16*)rf)[i]);
    else       x[i] = ((const float*)rf)[i];
}

// ---------- projections + frame transform ----------
// Original weight layouts W[l][kk(128)][col]. Each thread computes 4 consecutive
// output cols via uint2/float4 loads of W[kk][c0..c0+3] -> coalesced across lanes.
// k/kp written transposed AND 4-col packed per batch: k4[b][col/4][j(256)][4].
template<typename T>
__device__ void proj_body(int row, int tid, int l, float* sm,
    const float* __restrict__ x,
    const T* Wq, const T* Wk, const T* Wv,
    const T* Wqp, const T* Wkp, const T* Wvp,
    const T* rot, const T* pos,
    bf16* q, bf16* k, bf16* v, bf16* qpg, bf16* kpg, bf16* vpg)
{
    float* xr = sm;           // 128
    float* ob = sm + 128;     // 2016
    float* Rm = sm + 2144;    // 9
    float* tv = sm + 2153;    // 3

    if (tid < 128)          xr[tid]       = x[(size_t)row * 128 + tid];
    else if (tid < 137)     Rm[tid - 128] = LD(rot, (size_t)row * 9 + (tid - 128));
    else if (tid < 140)     tv[tid - 137] = LD(pos, (size_t)row * 3 + (tid - 137));
    __syncthreads();

    for (int c4 = tid; c4 < 504; c4 += 256) {
        int c = c4 * 4;
        const T* W; int col, wc;
        if (c < 1152) { int seg = c / 384; col = c - seg * 384; wc = 384;
                        W = ((seg == 0) ? Wq : (seg == 1 ? Wk : Wv)) + (size_t)l * 49152; }
        else          { int c2 = c - 1152; int seg = c2 / 288; col = c2 - seg * 288; wc = 288;
                        W = ((seg == 0) ? Wqp : (seg == 1 ? Wkp : Wvp)) + (size_t)l * 36864; }
        float a0 = 0.f, a1 = 0.f, a2 = 0.f, a3 = 0.f;
        if constexpr (sizeof(T) == 2) {
            const bf16* wp = (const bf16*)W + col;
            #pragma unroll 8
            for (int kk = 0; kk < 128; kk++) {
                union { uint2 u; bf16 h[4]; } cv;
                cv.u = *reinterpret_cast<const uint2*>(wp + (size_t)kk * wc);
                float xv = xr[kk];
                a0 += xv * b2f(cv.h[0]); a1 += xv * b2f(cv.h[1]);
                a2 += xv * b2f(cv.h[2]); a3 += xv * b2f(cv.h[3]);
            }
        } else {
            const float* wp = (const float*)W + col;
            #pragma unroll 8
            for (int kk = 0; kk < 128; kk++) {
                float4 p = *reinterpret_cast<const float4*>(wp + (size_t)kk * wc);
                float xv = xr[kk];
                a0 += xv * p.x; a1 += xv * p.y; a2 += xv * p.z; a3 += xv * p.w;
            }
        }
        ob[c] = a0; ob[c + 1] = a1; ob[c + 2] = a2; ob[c + 3] = a3;
    }
    __syncthreads();

    const int bb = row >> 8, ii = row & 255;

    for (int i2 = tid; i2 < 1152; i2 += 256) {
        bf16 val = f2b(ob[i2]);
        if (i2 < 384)      q[(size_t)row * 384 + i2] = val;
        else if (i2 < 768) {
            int col = i2 - 384;   // packed transposed
            k[(size_t)bb * 98304 + (size_t)(col >> 2) * 1024 + ii * 4 + (col & 3)] = val;
        }
        else               v[(size_t)row * 384 + (i2 - 768)] = val;
    }
    for (int pt = tid; pt < 288; pt += 256) {
        int ty = pt / 96; int ip = pt - ty * 96; int base = 1152 + ty * 288 + ip * 3;
        float p0 = ob[base], p1 = ob[base + 1], p2 = ob[base + 2];
        float g0 = Rm[0] * p0 + Rm[1] * p1 + Rm[2] * p2 + tv[0];
        float g1 = Rm[3] * p0 + Rm[4] * p1 + Rm[5] * p2 + tv[1];
        float g2 = Rm[6] * p0 + Rm[7] * p1 + Rm[8] * p2 + tv[2];
        float gg[3] = {g0, g1, g2};
        if (ty == 0) {
            qpg[(size_t)row * 288 + ip * 3 + 0] = f2b(g0);
            qpg[(size_t)row * 288 + ip * 3 + 1] = f2b(g1);
            qpg[(size_t)row * 288 + ip * 3 + 2] = f2b(g2);
        } else if (ty == 1) {  // packed transposed
            #pragma unroll
            for (int cc = 0; cc < 3; cc++) {
                int col = ip * 3 + cc;
                kpg[(size_t)bb * 73728 + (size_t)(col >> 2) * 1024 + ii * 4 + (col & 3)] = f2b(gg[cc]);
            }
        } else {
            vpg[(size_t)row * 288 + ip * 3 + 0] = f2b(g0);
            vpg[(size_t)row * 288 + ip * 3 + 1] = f2b(g1);
            vpg[(size_t)row * 288 + ip * 3 + 2] = f2b(g2);
        }
    }
}

__global__ __launch_bounds__(256) void k_proj(
    const float* __restrict__ x,
    const void* Wq, const void* Wk, const void* Wv,
    const void* Wqp, const void* Wkp, const void* Wvp,
    const void* rot, const void* pos,
    bf16* q, bf16* k, bf16* v, bf16* qpg, bf16* kpg, bf16* vpg,
    const int* __restrict__ flag, int l)
{
    extern __shared__ float smp[];
    int row = blockIdx.x, tid = threadIdx.x;
    if (*flag) proj_body<bf16>(row, tid, l, smp, x,
        (const bf16*)Wq, (const bf16*)Wk, (const bf16*)Wv,
        (const bf16*)Wqp, (const bf16*)Wkp, (const bf16*)Wvp,
        (const bf16*)rot, (const bf16*)pos, q, k, v, qpg, kpg, vpg);
    else proj_body<float>(row, tid, l, smp, x,
        (const float*)Wq, (const float*)Wk, (const float*)Wv,
        (const float*)Wqp, (const float*)Wkp, (const float*)Wvp,
        (const float*)rot, (const float*)pos, q, k, v, qpg, kpg, vpg);
}

// ---------- fused attention + Wo + LN1 + MLP + LN2 ----------
template<typename T>
__device__ void attn_body(int row, int tid, int l, char* smc,
    const bf16* q, const bf16* k, const bf16* v,
    const bf16* qpg, const bf16* kpg, const bf16* vpg,
    const T* z, const T* Wpb, const T* coef, const T* rot, const T* pos,
    float* __restrict__ x,
    const T* Wo, const T* bo, const T* g1, const T* b1ln,
    const T* w1, const T* bb1, const T* w2, const T* bb2,
    const T* w3, const T* bb3, const T* g2, const T* b2ln)
{
    const size_t oWpb = (size_t)l * 768, oCo = (size_t)l * 12;
    const size_t oB = (size_t)l * 128;

    float* fsm = (float*)smc;
    float* al   = fsm;                            // 12 x 260 = 3120 (16B-aligned rows)
    float* fr   = fsm + 3120;                     // 1824
    float* qi   = fsm + 4944;                     // 384
    float* qpi  = fsm + 5328;                     // 288
    float* wpb  = fsm + 5616;                     // 768
    float* chv  = fsm + 6384;                     // 12
    float* Rm   = fsm + 6396;                     // 9
    float* tv   = fsm + 6405;                     // 3
    float (*red)[8] = (float(*)[8])(fsm + 6408);  // 96
    float* red2 = fsm + 6504;                     // 8
    // total 6512 floats = 26048 B

    int b = row >> 8;

    for (int c2 = tid; c2 < 384; c2 += 256) qi[c2]  = b2f(q[(size_t)row * 384 + c2]);
    for (int c2 = tid; c2 < 288; c2 += 256) qpi[c2] = b2f(qpg[(size_t)row * 288 + c2]);
    for (int c2 = tid; c2 < 768; c2 += 256) wpb[c2] = LD(Wpb, oWpb + c2);
    if (tid < 12) { float cc = LD(coef, oCo + tid); chv[tid] = -log1pf(expf(cc)) * (1.f / 12.f); }
    else if (tid >= 16 && tid < 25) Rm[tid - 16] = LD(rot, (size_t)row * 9 + (tid - 16));
    else if (tid >= 25 && tid < 28) tv[tid - 25] = LD(pos, (size_t)row * 3 + (tid - 25));
    __syncthreads();

    const int j = tid;
    float lg[12];
    #pragma unroll
    for (int h = 0; h < 12; h++) lg[h] = 0.f;

    // logits_pair: lane j consumes z[row][j][0..63]; wpb read as 3x float4 per d
    if constexpr (sizeof(T) == 2) {
        const uint4* zr4 = reinterpret_cast<const uint4*>(z + (size_t)row * 16384 + (size_t)j * 64);
        #pragma unroll
        for (int u = 0; u < 8; u++) {
            union { uint4 q4; bf16 h8[8]; } c; c.q4 = zr4[u];
            #pragma unroll
            for (int dd = 0; dd < 8; dd++) {
                float zv = b2f(c.h8[dd]);
                const int d = u * 8 + dd;
                const float4* wp4 = reinterpret_cast<const float4*>(wpb + d * 12);
                float4 w0 = wp4[0], w1v = wp4[1], w2v = wp4[2];
                lg[0] += zv * w0.x;  lg[1] += zv * w0.y;  lg[2]  += zv * w0.z;  lg[3]  += zv * w0.w;
                lg[4] += zv * w1v.x; lg[5] += zv * w1v.y; lg[6]  += zv * w1v.z; lg[7]  += zv * w1v.w;
                lg[8] += zv * w2v.x; lg[9] += zv * w2v.y; lg[10] += zv * w2v.z; lg[11] += zv * w2v.w;
            }
        }
    } else {
        const float4* zr4 = reinterpret_cast<const float4*>(z + (size_t)row * 16384 + (size_t)j * 64);
        #pragma unroll
        for (int u = 0; u < 16; u++) {
            float4 pk = zr4[u];
            float zz[4] = {pk.x, pk.y, pk.z, pk.w};
            #pragma unroll
            for (int dd = 0; dd < 4; dd++) {
                float zv = zz[dd];
                const int d = u * 4 + dd;
                const float4* wp4 = reinterpret_cast<const float4*>(wpb + d * 12);
                float4 w0 = wp4[0], w1v = wp4[1], w2v = wp4[2];
                lg[0] += zv * w0.x;  lg[1] += zv * w0.y;  lg[2]  += zv * w0.z;  lg[3]  += zv * w0.w;
                lg[4] += zv * w1v.x; lg[5] += zv * w1v.y; lg[6]  += zv * w1v.z; lg[7]  += zv * w1v.w;
                lg[8] += zv * w2v.x; lg[9] += zv * w2v.y; lg[10] += zv * w2v.z; lg[11] += zv * w2v.w;
            }
        }
    }

    // packed transposed K / KP: uint2 (4 bf16 cols) per load, lane-coalesced
    const bf16* k4  = k   + (size_t)b * 98304;
    const bf16* kp4 = kpg + (size_t)b * 73728;
    #pragma unroll 2
    for (int h = 0; h < 12; h++) {
        float nd = 0.f;
        #pragma unroll
        for (int d4 = 0; d4 < 8; d4++) {
            union { uint2 q2; bf16 h4[4]; } c;
            c.q2 = *reinterpret_cast<const uint2*>(k4 + (size_t)(h * 8 + d4) * 1024 + j * 4);
            #pragma unroll
            for (int i = 0; i < 4; i++) nd += qi[h * 32 + d4 * 4 + i] * b2f(c.h4[i]);
        }
        float qk = 0.f, kp2h = 0.f, qp2h = 0.f;
        #pragma unroll
        for (int m4 = 0; m4 < 6; m4++) {
            union { uint2 q2; bf16 h4[4]; } c;
            c.q2 = *reinterpret_cast<const uint2*>(kp4 + (size_t)(h * 6 + m4) * 1024 + j * 4);
            #pragma unroll
            for (int i = 0; i < 4; i++) {
                float qv = qpi[h * 24 + m4 * 4 + i], kv = b2f(c.h4[i]);
                qk += qv * kv; kp2h += kv * kv; qp2h += qv * qv;
            }
        }
        float sp = chv[h] * (qp2h + kp2h - 2.f * qk);
        lg[h] = (lg[h] + nd * 0.17677669529663687f + sp) * 0.5773502691896258f;
    }

    int w = tid >> 6;
    #pragma unroll
    for (int h = 0; h < 12; h++) {
        float vv = lg[h];
        for (int off = 32; off; off >>= 1) vv = fmaxf(vv, __shfl_xor(vv, off, 64));
        if ((tid & 63) == 0) red[h][w] = vv;
    }
    __syncthreads();
    float mh[12];
    #pragma unroll
    for (int h = 0; h < 12; h++)
        mh[h] = fmaxf(fmaxf(red[h][0], red[h][1]), fmaxf(red[h][2], red[h][3]));
    #pragma unroll
    for (int h = 0; h < 12; h++) {
        float e = expf(lg[h] - mh[h]); lg[h] = e;
        float ss = e;
        for (int off = 32; off; off >>= 1) ss += __shfl_xor(ss, off, 64);
        if ((tid & 63) == 0) red[h][4 + w] = ss;
    }
    __syncthreads();
    #pragma unroll
    for (int h = 0; h < 12; h++) {
        float S = red[h][4] + red[h][5] + red[h][6] + red[h][7];
        al[h * AST + j] = lg[h] / S;
    }
    __syncthreads();

    // aggregation: thread g produces 8 consecutive outputs.
    // jj unrolled x4: one ds_read_b128 of alpha + 4 independent uint4 source loads.
    {
        int g = tid;
        if (g < 180) {
            int h, dst_kind, dsto = 0, d0 = 0;
            const bf16* srcb = nullptr; int stride = 0;
            if (g < 48)       { h = g >> 2; dsto = g * 8;
                                srcb = v + (size_t)b * 98304 + dsto; stride = 384; dst_kind = 0; }
            else if (g < 144) { int gg = g - 48; h = gg >> 3; d0 = (gg & 7) * 8; dst_kind = 1; }
            else              { int gg = g - 144; h = gg / 3; dsto = gg * 8;
                                srcb = vpg + (size_t)b * 73728 + dsto; stride = 288; dst_kind = 2; }

            float acc[8];
            #pragma unroll
            for (int i = 0; i < 8; i++) acc[i] = 0.f;
            const float* alh = al + h * AST;

            if (dst_kind != 1) {
                for (int jj = 0; jj < 256; jj += 4) {
                    float4 a4 = *reinterpret_cast<const float4*>(alh + jj);
                    union { uint4 q4; bf16 h8[8]; } c0, c1, c2, c3;
                    c0.q4 = *reinterpret_cast<const uint4*>(srcb + (size_t)(jj + 0) * stride);
                    c1.q4 = *reinterpret_cast<const uint4*>(srcb + (size_t)(jj + 1) * stride);
                    c2.q4 = *reinterpret_cast<const uint4*>(srcb + (size_t)(jj + 2) * stride);
                    c3.q4 = *reinterpret_cast<const uint4*>(srcb + (size_t)(jj + 3) * stride);
                    #pragma unroll
                    for (int i = 0; i < 8; i++) acc[i] += a4.x * b2f(c0.h8[i]);
                    #pragma unroll
                    for (int i = 0; i < 8; i++) acc[i] += a4.y * b2f(c1.h8[i]);
                    #pragma unroll
                    for (int i = 0; i < 8; i++) acc[i] += a4.z * b2f(c2.h8[i]);
                    #pragma unroll
                    for (int i = 0; i < 8; i++) acc[i] += a4.w * b2f(c3.h8[i]);
                }
            } else {
                if constexpr (sizeof(T) == 2) {
                    const bf16* zr = (const bf16*)z + (size_t)row * 16384 + d0;
                    for (int jj = 0; jj < 256; jj += 4) {
                        float4 a4 = *reinterpret_cast<const float4*>(alh + jj);
                        union { uint4 q4; bf16 h8[8]; } c0, c1, c2, c3;
                        c0.q4 = *reinterpret_cast<const uint4*>(zr + (size_t)(jj + 0) * 64);
                        c1.q4 = *reinterpret_cast<const uint4*>(zr + (size_t)(jj + 1) * 64);
                        c2.q4 = *reinterpret_cast<const uint4*>(zr + (size_t)(jj + 2) * 64);
                        c3.q4 = *reinterpret_cast<const uint4*>(zr + (size_t)(jj + 3) * 64);
                        #pragma unroll
                        for (int i = 0; i < 8; i++) acc[i] += a4.x * b2f(c0.h8[i]);
                        #pragma unroll
                        for (int i = 0; i < 8; i++) acc[i] += a4.y * b2f(c1.h8[i]);
                        #pragma unroll
                        for (int i = 0; i < 8; i++) acc[i] += a4.z * b2f(c2.h8[i]);
                        #pragma unroll
                        for (int i = 0; i < 8; i++) acc[i] += a4.w * b2f(c3.h8[i]);
                    }
                } else {
                    const float* zr = (const float*)z + (size_t)row * 16384 + d0;
                    for (int jj = 0; jj < 256; jj += 2) {
                        float2 a2 = *reinterpret_cast<const float2*>(alh + jj);
                        float4 p0 = *reinterpret_cast<const float4*>(zr + (size_t)(jj + 0) * 64);
                        float4 p1 = *reinterpret_cast<const float4*>(zr + (size_t)(jj + 0) * 64 + 4);
                        float4 p2 = *reinterpret_cast<const float4*>(zr + (size_t)(jj + 1) * 64);
                        float4 p3 = *reinterpret_cast<const float4*>(zr + (size_t)(jj + 1) * 64 + 4);
                        acc[0] += a2.x * p0.x; acc[1] += a2.x * p0.y; acc[2] += a2.x * p0.z; acc[3] += a2.x * p0.w;
                        acc[4] += a2.x * p1.x; acc[5] += a2.x * p1.y; acc[6] += a2.x * p1.z; acc[7] += a2.x * p1.w;
                        acc[0] += a2.y * p2.x; acc[1] += a2.y * p2.y; acc[2] += a2.y * p2.z; acc[3] += a2.y * p2.w;
                        acc[4] += a2.y * p3.x; acc[5] += a2.y * p3.y; acc[6] += a2.y * p3.z; acc[7] += a2.y * p3.w;
                    }
                }
            }
            if (dst_kind == 0) {
                #pragma unroll
                for (int i = 0; i < 8; i++) fr[dsto + i] = acc[i];
            } else if (dst_kind == 1) {
                int o = h * 64 + d0;
                #pragma unroll
                for (int i = 0; i < 8; i++) fr[384 + o + i] = acc[i];
            } else {
                #pragma unroll
                for (int i = 0; i < 8; i++) qpi[dsto + i] = acc[i];
            }
        }
    }
    __syncthreads();

    if (tid < 96) {
        int t3 = tid * 3;
        float u0 = qpi[t3 + 0] - tv[0], u1 = qpi[t3 + 1] - tv[1], u2 = qpi[t3 + 2] - tv[2];
        float f0 = Rm[0] * u0 + Rm[3] * u1 + Rm[6] * u2;
        float f1 = Rm[1] * u0 + Rm[4] * u1 + Rm[7] * u2;
        float f2 = Rm[2] * u0 + Rm[5] * u1 + Rm[8] * u2;
        float fd = sqrtf(f0 * f0 + f1 * f1 + f2 * f2);
        float inv = 1.f / (fd + 1e-4f);
        fr[1152 + t3 + 0] = f0; fr[1152 + t3 + 1] = f1; fr[1152 + t3 + 2] = f2;
        fr[1440 + tid] = fd;
        fr[1536 + t3 + 0] = f0 * inv; fr[1536 + t3 + 1] = f1 * inv; fr[1536 + t3 + 2] = f2 * inv;
    }
    __syncthreads();

    // ---- Wo: Wo[l][kk(1824)][col(128)], 32 col-groups x 8 kk-splits, unrolled x4 ----
    float* pacc = fsm;          // [8][128] = 1024 floats (al region is dead)
    float* shx  = fsm + 1024;   // 128
    int col = tid & 127;
    {
        int gC = tid & 31, s = tid >> 5;
        int c0 = gC * 4, kk0 = s * 228;
        float a0 = 0.f, a1p = 0.f, a2p = 0.f, a3p = 0.f;
        if constexpr (sizeof(T) == 2) {
            const bf16* wp = (const bf16*)Wo + (size_t)l * 233472 + c0;
            for (int kk = kk0; kk < kk0 + 228; kk += 4) {
                float4 f4 = *reinterpret_cast<const float4*>(fr + kk);
                union { uint2 u; bf16 h[4]; } v0, v1, v2, v3;
                v0.u = *reinterpret_cast<const uint2*>(wp + (size_t)(kk + 0) * 128);
                v1.u = *reinterpret_cast<const uint2*>(wp + (size_t)(kk + 1) * 128);
                v2.u = *reinterpret_cast<const uint2*>(wp + (size_t)(kk + 2) * 128);
                v3.u = *reinterpret_cast<const uint2*>(wp + (size_t)(kk + 3) * 128);
                a0 += f4.x * b2f(v0.h[0]); a1p += f4.x * b2f(v0.h[1]); a2p += f4.x * b2f(v0.h[2]); a3p += f4.x * b2f(v0.h[3]);
                a0 += f4.y * b2f(v1.h[0]); a1p += f4.y * b2f(v1.h[1]); a2p += f4.y * b2f(v1.h[2]); a3p += f4.y * b2f(v1.h[3]);
                a0 += f4.z * b2f(v2.h[0]); a1p += f4.z * b2f(v2.h[1]); a2p += f4.z * b2f(v2.h[2]); a3p += f4.z * b2f(v2.h[3]);
                a0 += f4.w * b2f(v3.h[0]); a1p += f4.w * b2f(v3.h[1]); a2p += f4.w * b2f(v3.h[2]); a3p += f4.w * b2f(v3.h[3]);
            }
        } else {
            const float* wp = (const float*)Wo + (size_t)l * 233472 + c0;
            for (int kk = kk0; kk < kk0 + 228; kk += 4) {
                float4 f4 = *reinterpret_cast<const float4*>(fr + kk);
                float4 p0 = *reinterpret_cast<const float4*>(wp + (size_t)(kk + 0) * 128);
                float4 p1 = *reinterpret_cast<const float4*>(wp + (size_t)(kk + 1) * 128);
                float4 p2 = *reinterpret_cast<const float4*>(wp + (size_t)(kk + 2) * 128);
                float4 p3 = *reinterpret_cast<const float4*>(wp + (size_t)(kk + 3) * 128);
                a0 += f4.x * p0.x; a1p += f4.x * p0.y; a2p += f4.x * p0.z; a3p += f4.x * p0.w;
                a0 += f4.y * p1.x; a1p += f4.y * p1.y; a2p += f4.y * p1.z; a3p += f4.y * p1.w;
                a0 += f4.z * p2.x; a1p += f4.z * p2.y; a2p += f4.z * p2.z; a3p += f4.z * p2.w;
                a0 += f4.w * p3.x; a1p += f4.w * p3.y; a2p += f4.w * p3.z; a3p += f4.w * p3.w;
            }
        }
        pacc[s * 128 + c0 + 0] = a0;  pacc[s * 128 + c0 + 1] = a1p;
        pacc[s * 128 + c0 + 2] = a2p; pacc[s * 128 + c0 + 3] = a3p;
    }
    __syncthreads();

    // fused dual block-reduction (one barrier pair for sum and sumsq)
    auto bsum2 = [&](float va, float vb, float& sa, float& sb) {
        for (int off = 32; off; off >>= 1) {
            va += __shfl_xor(va, off, 64);
            vb += __shfl_xor(vb, off, 64);
        }
        if ((tid & 63) == 0) { red2[tid >> 6] = va; red2[4 + (tid >> 6)] = vb; }
        __syncthreads();
        sa = red2[0] + red2[1] + red2[2] + red2[3];
        sb = red2[4] + red2[5] + red2[6] + red2[7];
        __syncthreads();
    };

    float val = x[(size_t)row * 128 + col] + LD(bo, oB + col);
    #pragma unroll
    for (int s = 0; s < 8; s++) val += pacc[s * 128 + col];

    float s1, s2;
    bsum2(val, val * val, s1, s2);
    float mean = s1 * (1.f / 256.f);
    float var = s2 * (1.f / 256.f) - mean * mean;
    float xl = (val - mean) * rsqrtf(var + 1e-5f) * LD(g1, oB + col) + LD(b1ln, oB + col);
    shx[col] = xl;
    __syncthreads();

    // ---- MLP: w[l][kk(128)][col(128)], 32 col-groups x 8 kk-splits, unrolled x4 ----
    const size_t oM = (size_t)l * 16384;
    int gC = tid & 31, s8 = tid >> 5;
    int c0 = gC * 4, kkm = s8 * 16;

    auto mlp_partial = [&](const T* W) {
        float a0 = 0.f, a1p = 0.f, a2p = 0.f, a3p = 0.f;
        if constexpr (sizeof(T) == 2) {
            const bf16* wp = (const bf16*)W + oM + c0;
            #pragma unroll
            for (int kk = kkm; kk < kkm + 16; kk += 4) {
                float4 f4 = *reinterpret_cast<const float4*>(shx + kk);
                union { uint2 u; bf16 h[4]; } v0, v1, v2, v3;
                v0.u = *reinterpret_cast<const uint2*>(wp + (size_t)(kk + 0) * 128);
                v1.u = *reinterpret_cast<const uint2*>(wp + (size_t)(kk + 1) * 128);
                v2.u = *reinterpret_cast<const uint2*>(wp + (size_t)(kk + 2) * 128);
                v3.u = *reinterpret_cast<const uint2*>(wp + (size_t)(kk + 3) * 128);
                a0 += f4.x * b2f(v0.h[0]); a1p += f4.x * b2f(v0.h[1]); a2p += f4.x * b2f(v0.h[2]); a3p += f4.x * b2f(v0.h[3]);
                a0 += f4.y * b2f(v1.h[0]); a1p += f4.y * b2f(v1.h[1]); a2p += f4.y * b2f(v1.h[2]); a3p += f4.y * b2f(v1.h[3]);
                a0 += f4.z * b2f(v2.h[0]); a1p += f4.z * b2f(v2.h[1]); a2p += f4.z * b2f(v2.h[2]); a3p += f4.z * b2f(v2.h[3]);
                a0 += f4.w * b2f(v3.h[0]); a1p += f4.w * b2f(v3.h[1]); a2p += f4.w * b2f(v3.h[2]); a3p += f4.w * b2f(v3.h[3]);
            }
        } else {
            const float* wp = (const float*)W + oM + c0;
            #pragma unroll
            for (int kk = kkm; kk < kkm + 16; kk += 4) {
                float4 f4 = *reinterpret_cast<const float4*>(shx + kk);
                float4 p0 = *reinterpret_cast<const float4*>(wp + (size_t)(kk + 0) * 128);
                float4 p1 = *reinterpret_cast<const float4*>(wp + (size_t)(kk + 1) * 128);
                float4 p2 = *reinterpret_cast<const float4*>(wp + (size_t)(kk + 2) * 128);
                float4 p3 = *reinterpret_cast<const float4*>(wp + (size_t)(kk + 3) * 128);
                a0 += f4.x * p0.x; a1p += f4.x * p0.y; a2p += f4.x * p0.z; a3p += f4.x * p0.w;
                a0 += f4.y * p1.x; a1p += f4.y * p1.y; a2p += f4.y * p1.z; a3p += f4.y * p1.w;
                a0 += f4.z * p2.x; a1p += f4.z * p2.y; a2p += f4.z * p2.z; a3p += f4.z * p2.w;
                a0 += f4.w * p3.x; a1p += f4.w * p3.y; a2p += f4.w * p3.z; a3p += f4.w * p3.w;
            }
        }
        pacc[s8 * 128 + c0 + 0] = a0;  pacc[s8 * 128 + c0 + 1] = a1p;
        pacc[s8 * 128 + c0 + 2] = a2p; pacc[s8 * 128 + c0 + 3] = a3p;
    };

    mlp_partial(w1);
    __syncthreads();
    float a1 = LD(bb1, oB + col);
    #pragma unroll
    for (int s = 0; s < 8; s++) a1 += pacc[s * 128 + col];
    shx[col] = fmaxf(a1, 0.f);
    __syncthreads();

    mlp_partial(w2);
    __syncthreads();
    float a2 = LD(bb2, oB + col);
    #pragma unroll
    for (int s = 0; s < 8; s++) a2 += pacc[s * 128 + col];
    shx[col] = fmaxf(a2, 0.f);
    __syncthreads();

    mlp_partial(w3);
    __syncthreads();
    float a3 = LD(bb3, oB + col);
    #pragma unroll
    for (int s = 0; s < 8; s++) a3 += pacc[s * 128 + col];
    float val2 = xl + a3;

    float t1, t2;
    bsum2(val2, val2 * val2, t1, t2);
    float mean2 = t1 * (1.f / 256.f);
    float var2 = t2 * (1.f / 256.f) - mean2 * mean2;
    if (tid < 128)
        x[(size_t)row * 128 + col] = (val2 - mean2) * rsqrtf(var2 + 1e-5f) * LD(g2, oB + col) + LD(b2ln, oB + col);
}

__global__ __launch_bounds__(256, 4) void k_attn_post(
    const bf16* q, const bf16* k, const bf16* v,
    const bf16* qpg, const bf16* kpg, const bf16* vpg,
    const void* z, const void* Wpb, const void* coef, const void* rot, const void* pos,
    float* x,
    const void* Wo, const void* bo, const void* g1, const void* b1ln,
    const void* w1, const void* bb1, const void* w2, const void* bb2,
    const void* w3, const void* bb3, const void* g2, const void* b2ln,
    const int* __restrict__ flag, int l)
{
    extern __shared__ char smc[];
    int row = blockIdx.x, tid = threadIdx.x;
    if (*flag) attn_body<bf16>(row, tid, l, smc, q, k, v, qpg, kpg, vpg,
        (const bf16*)z, (const bf16*)Wpb, (const bf16*)coef, (const bf16*)rot, (const bf16*)pos, x,
        (const bf16*)Wo, (const bf16*)bo, (const bf16*)g1, (const bf16*)b1ln,
        (const bf16*)w1, (const bf16*)bb1, (const bf16*)w2, (const bf16*)bb2,
        (const bf16*)w3, (const bf16*)bb3, (const bf16*)g2, (const bf16*)b2ln);
    else attn_body<float>(row, tid, l, smc, q, k, v, qpg, kpg, vpg,
        (const float*)z, (const float*)Wpb, (const float*)coef, (const float*)rot, (const float*)pos, x,
        (const float*)Wo, (const float*)bo, (const float*)g1, (const float*)b1ln,
        (const float*)w1, (const float*)bb1, (const float*)w2, (const float*)bb2,
        (const float*)w3, (const float*)bb3, (const float*)g2, (const float*)b2ln);
}

// ---------- regression head ----------
__global__ void k_final(const float* __restrict__ x, const void* Wreg, const void* breg,
                        void* out, const int* __restrict__ flag)
{
    int idx = blockIdx.x * 256 + threadIdx.x;
    int isBF = *flag;
    int b = idx >> 7, r = (idx >> 2) & 31, c = idx & 3;
    const float* xr = x + ((size_t)(b * 256 + 224 + r)) * 128;
    if (isBF) {
        const bf16* W = (const bf16*)Wreg;
        float acc = b2f(((const bf16*)breg)[c]);
        for (int kk = 0; kk < 128; kk++) acc += xr[kk] * b2f(W[kk * 4 + c]);
        ((bf16*)out)[idx] = f2b(acc);
    } else {
        const float* W = (const float*)Wreg;
        float acc = ((const float*)breg)[c];
        for (int kk = 0; kk < 128; kk++) acc += xr[kk] * W[kk * 4 + c];
        ((float*)out)[idx] = acc;
    }
}

extern "C" void kernel_launch(void* const* d_in, const int* in_sizes, int n_in,
                              void* d_out, int out_size, void* d_ws, size_t ws_size,
                              hipStream_t stream)
{
    const void* rot  = d_in[0];
    const void* pos  = d_in[1];
    const void* resf = d_in[2];
    const void* pair = d_in[3];
    const void* Wq   = d_in[5];
    const void* Wk   = d_in[6];
    const void* Wv   = d_in[7];
    const void* Wpb  = d_in[8];
    const void* coef = d_in[9];
    const void* Wqp  = d_in[10];
    const void* Wkp  = d_in[11];
    const void* Wvp  = d_in[12];
    const void* Wo   = d_in[13];
    const void* bo   = d_in[14];
    const void* ln1g = d_in[15];
    const void* ln1b = d_in[16];
    const void* w1   = d_in[17];
    const void* b1   = d_in[18];
    const void* w2   = d_in[19];
    const void* b2   = d_in[20];
    const void* w3   = d_in[21];
    const void* b3   = d_in[22];
    const void* ln2g = d_in[23];
    const void* ln2b = d_in[24];
    const void* Wreg = d_in[25];
    const void* breg = d_in[26];

    char* base = (char*)d_ws;
    int*   flag = (int*)base;
    float* X    = (float*)(base + 64);
    size_t off  = 64 + (size_t)BL * 128 * 4;
    bf16* Qb   = (bf16*)(base + off); off += (size_t)BL * 384 * 2;
    bf16* Kb   = (bf16*)(base + off); off += (size_t)BL * 384 * 2;
    bf16* Vb   = (bf16*)(base + off); off += (size_t)BL * 384 * 2;
    bf16* QPGb = (bf16*)(base + off); off += (size_t)BL * 288 * 2;
    bf16* KPGb = (bf16*)(base + off); off += (size_t)BL * 288 * 2;
    bf16* VPGb = (bf16*)(base + off); off += (size_t)BL * 288 * 2;

    const size_t SM_PROJ = 2156 * sizeof(float);
    const size_t SM_ATTN = 6512 * sizeof(float);   // 26048 B

    k_sniff<<<1, 64, 0, stream>>>(rot, flag);
    k_init<<<BL * 128 / 256, 256, 0, stream>>>(resf, X, flag);

    for (int l = 0; l < 6; l++) {
        k_proj<<<BL, 256, SM_PROJ, stream>>>(
            X, Wq, Wk, Wv, Wqp, Wkp, Wvp, rot, pos,
            Qb, Kb, Vb, QPGb, KPGb, VPGb, flag, l);
        k_attn_post<<<BL, 256, SM_ATTN, stream>>>(
            Qb, Kb, Vb, QPGb, KPGb, VPGb,
            pair, Wpb, coef, rot, pos, X,
            Wo, bo, ln1g, ln1b, w1, b1, w2, b2, w3, b3, ln2g, ln2b, flag, l);
    }

    k_final<<<4, 256, 0, stream>>>(X, Wreg, breg, d_out, flag);
}